// Round 1
// baseline (6696.138 us; speedup 1.0000x reference)
//
#include <hip/hip_runtime.h>
#include <math.h>

// CV-photonic circuit simulator: WIRES=4, LAYERS=2, CUTOFF=10, BATCH=2048.
// Strategy: one block per batch element, full 10^4-complex state in LDS.
// BS applied via exact total-photon-number block-diagonal structure (670 nnz).
// CX applied via exact factorization exp(x⊗Q) = (V⊗I) diag_n exp(λ_n Q) (V^T⊗I).
// All ≤10x10 expm done on-device in fp64 (scale 2^-10, Taylor 12, square 10).

namespace {

constexpr int NTB = 512;                 // threads per state block (8 waves)
constexpr int SMEM_BYTES = 99456;        // dynamic LDS for state kernel
constexpr double THETA = 0.7853981633974483096; // pi/4

struct cxf { float x, y; };
struct cxd { double x, y; };

// Generator entry (i,j) for squeeze: M = 0.5*(conj(z)*a^2 - z*ad^2)
__device__ __forceinline__ cxd gen_squeeze(int i, int j, double zr, double zi){
  if (j == i+2){ double g = 0.5*sqrt((double)((i+1)*(i+2))); return {zr*g, -zi*g}; }
  if (i == j+2){ double g = 0.5*sqrt((double)((j+1)*(j+2))); return {-zr*g, -zi*g}; }
  return {0.0, 0.0};
}
// Generator entry (i,j) for displacement: M = a*ad - conj(a)*a_op
__device__ __forceinline__ cxd gen_disp(int i, int j, double ar, double ai){
  if (i == j+1){ double g = sqrt((double)i); return {ar*g, ai*g}; }
  if (j == i+1){ double g = sqrt((double)j); return {-ar*g, ai*g}; }
  return {0.0, 0.0};
}

// Wave-cooperative fixed-schedule expm: result = exp(M), n x n (n<=10), row-major.
// Buffers are per-wave LDS cxd[100]. Result ends in the ORIGINAL R buffer
// (squaring loop swaps an even number of times). Uniform barriers: must be
// called by ALL threads; `act` gates the work.
__device__ void expm_fixed(bool act, int n, cxd* M, cxd* P, cxd* T, cxd* R, int lane){
  const int n2 = n*n;
  if (act){
    for (int e=lane; e<n2; e+=64){ M[e].x *= 0x1p-10; M[e].y *= 0x1p-10; }
    for (int e=lane; e<n2; e+=64){
      P[e] = M[e];
      cxd r = M[e];
      if (e % (n+1) == 0) r.x += 1.0;   // + identity on diagonal
      R[e] = r;
    }
  }
  __syncthreads();
  for (int t=2; t<=12; ++t){
    if (act){
      double inv = 1.0/(double)t;
      for (int e=lane; e<n2; e+=64){
        int i = e/n, j = e - i*n;
        double ax=0.0, ay=0.0;
        for (int k=0;k<n;k++){
          cxd p = P[i*n+k], m = M[k*n+j];
          ax += p.x*m.x - p.y*m.y;
          ay += p.x*m.y + p.y*m.x;
        }
        T[e] = {ax*inv, ay*inv};
      }
    }
    __syncthreads();
    { cxd* tmp = P; P = T; T = tmp; }
    if (act){ for (int e=lane; e<n2; e+=64){ R[e].x += P[e].x; R[e].y += P[e].y; } }
    __syncthreads();
  }
  for (int s=0; s<10; ++s){
    if (act){
      for (int e=lane; e<n2; e+=64){
        int i = e/n, j = e - i*n;
        double ax=0.0, ay=0.0;
        for (int k=0;k<n;k++){
          cxd p = R[i*n+k], q = R[k*n+j];
          ax += p.x*q.x - p.y*q.y;
          ay += p.x*q.y + p.y*q.x;
        }
        T[e] = {ax, ay};
      }
    }
    __syncthreads();
    { cxd* tmp = R; R = T; T = tmp; }
    __syncthreads();
  }
}

// ---------------- Kernel A: shared gate matrices into d_ws -----------------
// ws layout (floats): V[100] | W[10*100] | BS packed cxf[670] | U_lay cxf[8*100]
__global__ __launch_bounds__(256)
void gates_kernel(const float* __restrict__ dmag, const float* __restrict__ dphase,
                  const float* __restrict__ smag, const float* __restrict__ sphase,
                  float* __restrict__ wsf){
  __shared__ double lam[10];
  __shared__ double scr[4][4][200];     // [wave][buf] cxd[100]
  __shared__ double layres[16][200];    // S_lay (0..7), D_lay (8..15) results
  const int tid = threadIdx.x;
  const int wv = tid >> 6, lane = tid & 63;
  float* ws_V = wsf;
  float* ws_W = wsf + 100;
  cxf* ws_BS = (cxf*)(wsf + 1100);
  cxf* ws_UL = (cxf*)(wsf + 2440);
  const int OFF[19] = {0,1,5,14,30,55,91,140,204,285,385,466,530,579,615,640,656,665,669};

  // Eigendecomposition of x = a+ad (symmetric tridiagonal, offdiag sqrt(k)).
  // Sturm bisection per eigenvalue (threads 0..9), eigenvector by recurrence.
  if (tid < 10){
    double lo = -6.0, hi = 6.0;   // Gershgorin bound ~5.83
    for (int it=0; it<80; ++it){
      double mid = 0.5*(lo+hi);
      int cnt = 0; double q = 1.0;
      for (int i=0;i<10;i++){
        q = -mid - (i ? (double)i/q : 0.0);   // b_{i-1}^2 = i, diag = 0
        if (fabs(q) < 1e-300) q = -1e-300;
        if (q < 0.0) cnt++;
      }
      if (cnt > tid) hi = mid; else lo = mid;
    }
    double x = 0.5*(lo+hi);
    double p[10];
    p[0] = 1.0; p[1] = x;
    for (int k=1;k<9;k++) p[k+1] = (x*p[k] - sqrt((double)k)*p[k-1]) * (1.0/sqrt((double)(k+1)));
    double nn=0.0; for (int k=0;k<10;k++) nn += p[k]*p[k];
    double inv = 1.0/sqrt(nn);
    lam[tid] = x;
    for (int k=0;k<10;k++) ws_V[k*10+tid] = (float)(p[k]*inv);  // V[k][m]
  }
  __syncthreads();

  // 45 expm tasks: t<10: W[n]=exp(lam_n*Q); 10..28: BS block n=t-10; 29..44: layer S/D.
  for (int round=0; round<12; ++round){
    int t = round*4 + wv;
    bool act = (t < 45);
    int n = 10, bn = 0, ilo = 0;
    if (act && t >= 10 && t < 29){
      bn = t - 10; ilo = bn < 10 ? 0 : bn - 9;
      int ihi = bn < 10 ? bn : 9;
      n = ihi - ilo + 1;
    }
    cxd* M = (cxd*)scr[wv][0];
    cxd* P = (cxd*)scr[wv][1];
    cxd* T = (cxd*)scr[wv][2];
    cxd* R = (cxd*)scr[wv][3];
    if (act){
      if (t < 10){
        double l = lam[t];   // Q = -0.5*(a - ad), real antisymmetric
        for (int e=lane; e<100; e+=64){
          int i=e/10, j=e-10*i;
          double v = 0.0;
          if (j == i+1) v = -0.5*l*sqrt((double)(i+1));
          else if (i == j+1) v = 0.5*l*sqrt((double)i);
          M[e] = {v, 0.0};
        }
      } else if (t < 29){
        // BS block n: i*theta * symmetric tridiagonal
        for (int e=lane; e<n*n; e+=64){
          int r=e/n, c=e-n*r;
          double v = 0.0;
          if (c == r+1) v = THETA*sqrt((double)((ilo+r+1)*(bn-ilo-r)));
          else if (r == c+1) v = THETA*sqrt((double)((ilo+c+1)*(bn-ilo-c)));
          M[e] = {0.0, v};
        }
      } else {
        int idx = t-29, kind = idx>>3, L=(idx>>2)&1, w=idx&3;
        double r_ = kind ? (double)dmag[L*4+w]   : (double)smag[L*4+w];
        double ph = kind ? (double)dphase[L*4+w] : (double)sphase[L*4+w];
        double zr = r_*cos(ph), zi = r_*sin(ph);
        for (int e=lane; e<100; e+=64){
          int i=e/10, j=e-10*i;
          M[e] = kind ? gen_disp(i,j,zr,zi) : gen_squeeze(i,j,zr,zi);
        }
      }
    }
    __syncthreads();
    expm_fixed(act, n, M, P, T, R, lane);
    if (act){
      if (t < 10){
        for (int e=lane;e<100;e+=64) ws_W[t*100+e] = (float)R[e].x;  // real matrix
      } else if (t < 29){
        for (int e=lane;e<n*n;e+=64){ cxf o; o.x=(float)R[e].x; o.y=(float)R[e].y; ws_BS[OFF[bn]+e]=o; }
      } else {
        int idx = t-29;
        cxd* dst = (cxd*)layres[idx];
        for (int e=lane;e<100;e+=64) dst[e] = R[e];
      }
    }
    __syncthreads();
  }
  // Fuse layer gates: U_lay[f] = D_lay * S_lay (S applied first), f = L*4+w
  for (int half=0; half<2; ++half){
    int f = wv + half*4;
    cxd* D  = (cxd*)layres[8+f];
    cxd* Sm = (cxd*)layres[f];
    for (int e=lane;e<100;e+=64){
      int i=e/10, j=e-10*i;
      double ax=0, ay=0;
      for (int k=0;k<10;k++){
        cxd d=D[i*10+k], s=Sm[k*10+j];
        ax += d.x*s.x - d.y*s.y;
        ay += d.x*s.y + d.y*s.x;
      }
      cxf o; o.x=(float)ax; o.y=(float)ay;
      ws_UL[f*100+e] = o;
    }
  }
}

// ---------------- Kernel B: the circuit, state resident in LDS -------------

// Single-mode complex gate, in-place (thread owns whole 10-elem fiber).
__device__ __forceinline__ void apply1_c(cxf* S, const cxf* __restrict__ U, int m, int tid){
  const int STR[4] = {1000,100,10,1};
  const int sm = STR[m];
  const int r0 = (m==0)?1:0, r1=(m<=1)?2:1, r2=(m<=2)?3:2;
  const int s0=STR[r0], s1=STR[r1], s2=STR[r2];
  for (int f0=0; f0<1024; f0+=NTB){
    int f = f0 + tid;
    if (f < 1000){
      int c0=f/100, rem=f-100*c0, c1=rem/10, c2=rem-10*c1;
      int base = c0*s0 + c1*s1 + c2*s2;
      cxf v[10];
      #pragma unroll
      for (int k=0;k<10;k++) v[k] = S[base + k*sm];
      cxf o[10];
      #pragma unroll
      for (int i=0;i<10;i++){
        float ax=0.f, ay=0.f;
        #pragma unroll
        for (int k=0;k<10;k++){
          cxf u = U[i*10+k];
          ax += u.x*v[k].x - u.y*v[k].y;
          ay += u.x*v[k].y + u.y*v[k].x;
        }
        o[i].x=ax; o[i].y=ay;
      }
      #pragma unroll
      for (int i=0;i<10;i++) S[base + i*sm] = o[i];
    }
  }
}

// Single-mode REAL gate (V or V^T), in-place.
__device__ __forceinline__ void apply1_r(cxf* S, const float* __restrict__ Vm, int m, bool trans, int tid){
  const int STR[4] = {1000,100,10,1};
  const int sm = STR[m];
  const int r0 = (m==0)?1:0, r1=(m<=1)?2:1, r2=(m<=2)?3:2;
  const int s0=STR[r0], s1=STR[r1], s2=STR[r2];
  for (int f0=0; f0<1024; f0+=NTB){
    int f = f0 + tid;
    if (f < 1000){
      int c0=f/100, rem=f-100*c0, c1=rem/10, c2=rem-10*c1;
      int base = c0*s0 + c1*s1 + c2*s2;
      cxf v[10];
      #pragma unroll
      for (int k=0;k<10;k++) v[k] = S[base + k*sm];
      cxf o[10];
      #pragma unroll
      for (int i=0;i<10;i++){
        float ax=0.f, ay=0.f;
        #pragma unroll
        for (int k=0;k<10;k++){
          float u = trans ? Vm[k*10+i] : Vm[i*10+k];
          ax += u*v[k].x;
          ay += u*v[k].y;
        }
        o[i].x=ax; o[i].y=ay;
      }
      #pragma unroll
      for (int i=0;i<10;i++) S[base + i*sm] = o[i];
    }
  }
}

// Conditional real gate on m2, matrix W[n] selected by m1 coordinate (eigenbasis).
__device__ __forceinline__ void applyW(cxf* S, const float* __restrict__ Wall, int m1, int m2, int tid){
  const int STR[4] = {1000,100,10,1};
  const int sm = STR[m2];
  const int r0 = (m2==0)?1:0, r1=(m2<=1)?2:1, r2=(m2<=2)?3:2;
  const int s0=STR[r0], s1=STR[r1], s2=STR[r2];
  const int pos = (m1==r0)?0:((m1==r1)?1:2);
  for (int f0=0; f0<1024; f0+=NTB){
    int f = f0 + tid;
    if (f < 1000){
      int c0=f/100, rem=f-100*c0, c1=rem/10, c2=rem-10*c1;
      int base = c0*s0 + c1*s1 + c2*s2;
      int n = (pos==0)?c0:((pos==1)?c1:c2);
      const float* Wm = Wall + n*100;
      cxf v[10];
      #pragma unroll
      for (int k=0;k<10;k++) v[k] = S[base + k*sm];
      cxf o[10];
      #pragma unroll
      for (int i=0;i<10;i++){
        float ax=0.f, ay=0.f;
        #pragma unroll
        for (int k=0;k<10;k++){
          float u = Wm[i*10+k];
          ax += u*v[k].x;
          ay += u*v[k].y;
        }
        o[i].x=ax; o[i].y=ay;
      }
      #pragma unroll
      for (int i=0;i<10;i++) S[base + i*sm] = o[i];
    }
  }
}

// Beamsplitter via total-photon-number blocks, in-place (thread owns sub-fiber).
__device__ __forceinline__ void applyBS(cxf* S, const cxf* __restrict__ BSp, int m1, int m2, int tid){
  const int STR[4] = {1000,100,10,1};
  const int OFF[19] = {0,1,5,14,30,55,91,140,204,285,385,466,530,579,615,640,656,665,669};
  int ra=-1, rb=-1;
  for (int q=0;q<4;q++) if (q!=m1 && q!=m2){ if (ra<0) ra=q; else rb=q; }
  const int sa=STR[ra], sb=STR[rb], s1=STR[m1], s2=STR[m2];
  for (int w0=0; w0<2048; w0+=NTB){
    int it = w0 + tid;
    if (it < 1900){
      int rest = it/19, bn = it - 19*rest;
      int ilo = bn<10?0:bn-9, ihi = bn<10?bn:9, sz = ihi-ilo+1;
      int ca = rest/10, cb = rest-10*ca;
      int base = ca*sa + cb*sb;
      const cxf* Bn = BSp + OFF[bn];
      cxf v[10];
      #pragma unroll
      for (int r=0;r<10;r++){
        if (r < sz){ int i=ilo+r; v[r] = S[base + i*s1 + (bn-i)*s2]; }
      }
      cxf o[10];
      #pragma unroll
      for (int r=0;r<10;r++){
        if (r < sz){
          float ax=0.f, ay=0.f;
          for (int c=0;c<sz;c++){
            cxf u = Bn[r*sz+c];
            ax += u.x*v[c].x - u.y*v[c].y;
            ay += u.x*v[c].y + u.y*v[c].x;
          }
          o[r].x=ax; o[r].y=ay;
        }
      }
      #pragma unroll
      for (int r=0;r<10;r++){
        if (r < sz){ int i=ilo+r; S[base + i*s1 + (bn-i)*s2] = o[r]; }
      }
    }
  }
}

__global__ __launch_bounds__(NTB)
void state_kernel(const float* __restrict__ jets, const float* __restrict__ sscale,
                  const float* __restrict__ wd, const float* __restrict__ bd,
                  const float* __restrict__ wsf, float* __restrict__ out){
  extern __shared__ __align__(16) char smem[];
  cxf* S    = (cxf*)smem;                 // 10000 cxf  (80000 B)
  cxf* UE   = (cxf*)(smem + 80000);       // 4*100 fused encoding gates
  cxf* UL   = (cxf*)(smem + 83200);       // 8*100 fused layer gates
  float* V  = (float*)(smem + 89600);     // 100
  float* W  = (float*)(smem + 90000);     // 10*100
  cxf* BSm  = (cxf*)(smem + 94000);       // 670 packed BS blocks
  float* red = (float*)(smem + 99360);    // 8

  const int tid = threadIdx.x, wv = tid>>6, lane = tid&63;
  const int b = blockIdx.x;

  // Load shared gate tables from ws (4040 floats).
  for (int i=tid; i<4040; i+=NTB){
    float v = wsf[i];
    if (i < 100) V[i] = v;
    else if (i < 1100) W[i-100] = v;
    else if (i < 2440) ((float*)BSm)[i-1100] = v;
    else ((float*)UL)[i-2440] = v;
  }

  // Per-block encoding expms (scratch overlaps the not-yet-initialized state).
  cxd* M = (cxd*)(smem + wv*6400);
  cxd* P = M + 100; cxd* T = M + 200; cxd* R = M + 300;
  cxd* res = (cxd*)(smem + 51200) + wv*100;
  {
    int w = wv & 3, kind = wv >> 2;   // waves 0-3: squeeze; 4-7: displacement
    double eta = (double)jets[b*12 + w*3 + 0];
    double jph = (double)jets[b*12 + w*3 + 1];
    double pt  = (double)jets[b*12 + w*3 + 2];
    double zr, zi;
    if (kind == 0){ double phs = pt*jph*0.5; zr = eta*cos(phs); zi = eta*sin(phs); }
    else {
      double sc = 10.0/(1.0 + exp(-(double)sscale[0])) + 0.01;
      double mag = sc*pt; zr = mag*cos(eta); zi = mag*sin(eta);
    }
    for (int e=lane; e<100; e+=64){
      int i=e/10, j=e-10*i;
      M[e] = kind ? gen_disp(i,j,zr,zi) : gen_squeeze(i,j,zr,zi);
    }
  }
  __syncthreads();
  expm_fixed(true, 10, M, P, T, R, lane);
  for (int e=lane; e<100; e+=64) res[e] = R[e];
  __syncthreads();
  // Fuse: U_enc[w] = D_enc * S_enc (squeeze applied first)
  if (wv < 4){
    cxd* Dm = (cxd*)(smem + 51200) + (4+wv)*100;
    cxd* Sm = (cxd*)(smem + 51200) + wv*100;
    for (int e=lane; e<100; e+=64){
      int i=e/10, j=e-10*i;
      double ax=0, ay=0;
      for (int k=0;k<10;k++){
        cxd d=Dm[i*10+k], s=Sm[k*10+j];
        ax += d.x*s.x - d.y*s.y;
        ay += d.x*s.y + d.y*s.x;
      }
      cxf o; o.x=(float)ax; o.y=(float)ay;
      UE[wv*100+e] = o;
    }
  }
  __syncthreads();

  // Init state |0,0,0,0>
  for (int e=tid; e<10000; e+=NTB){ cxf z; z.x = (e==0)?1.f:0.f; z.y = 0.f; S[e] = z; }
  __syncthreads();

  // Encoding gates
  for (int w=0; w<4; ++w){ apply1_c(S, UE + w*100, w, tid); __syncthreads(); }

  const int CXP[6][2] = {{0,1},{0,2},{0,3},{1,2},{1,3},{2,3}};
  const int BSP[4][2] = {{0,1},{1,2},{2,3},{3,0}};
  for (int L=0; L<2; ++L){
    for (int p=0; p<6; ++p){
      int m1 = CXP[p][0], m2 = CXP[p][1];
      apply1_r(S, V, m1, true, tid);  __syncthreads();   // V^T on m1
      applyW(S, W, m1, m2, tid);      __syncthreads();   // exp(lam_n Q) on m2
      apply1_r(S, V, m1, false, tid); __syncthreads();   // V on m1
    }
    for (int p=0; p<4; ++p){ applyBS(S, BSm, BSP[p][0], BSP[p][1], tid); __syncthreads(); }
    for (int w=0; w<4; ++w){ apply1_c(S, UL + (L*4+w)*100, w, tid); __syncthreads(); }
  }

  // Reduction: out[b] = sum |psi|^2 (w0*n0 + w1*n1 + w2*n2) + bias
  float w0 = wd[0], w1 = wd[1], w2 = wd[2];
  float acc = 0.f;
  for (int e=tid; e<10000; e+=NTB){
    cxf z = S[e];
    float p = z.x*z.x + z.y*z.y;
    int n0 = e/1000, r_ = e-1000*n0, n1 = r_/100, r2_ = r_-100*n1, n2 = r2_/10;
    acc += p * ((float)n0*w0 + (float)n1*w1 + (float)n2*w2);
  }
  for (int off=32; off; off>>=1) acc += __shfl_down(acc, off, 64);
  if (lane == 0) red[wv] = acc;
  __syncthreads();
  if (tid == 0){
    float s = 0.f;
    for (int i=0;i<8;i++) s += red[i];
    out[b] = s + bd[0];
  }
}

} // anonymous namespace

extern "C" void kernel_launch(void* const* d_in, const int* in_sizes, int n_in,
                              void* d_out, int out_size, void* d_ws, size_t ws_size,
                              hipStream_t stream){
  const float* jets   = (const float*)d_in[0];
  const float* sscale = (const float*)d_in[1];
  const float* dmag   = (const float*)d_in[2];
  const float* dphase = (const float*)d_in[3];
  const float* smag   = (const float*)d_in[4];
  const float* sphase = (const float*)d_in[5];
  const float* wd     = (const float*)d_in[6];
  const float* bd     = (const float*)d_in[7];
  float* out = (float*)d_out;
  float* wsf = (float*)d_ws;
  int B = in_sizes[0] / 12;   // jets is (B, 4, 3)

  // Opt-in to >64KB dynamic LDS (state kernel uses ~97KB). Same call every
  // launch (no static guards); harmless if already set.
  (void)hipFuncSetAttribute(reinterpret_cast<const void*>(&state_kernel),
                            hipFuncAttributeMaxDynamicSharedMemorySize, SMEM_BYTES);

  gates_kernel<<<1, 256, 0, stream>>>(dmag, dphase, smag, sphase, wsf);
  state_kernel<<<B, NTB, SMEM_BYTES, stream>>>(jets, sscale, wd, bd, wsf, out);
}

// Round 3
// 3641.458 us; speedup vs baseline: 1.8389x; 1.8389x over previous
//
#include <hip/hip_runtime.h>
#include <math.h>

// CV-photonic circuit: WIRES=4, LAYERS=2, CUTOFF=10, BATCH=2048.
// R3 (=R2 fixed): state-only LDS (80,384 B -> 2 blocks/CU), gate tables in
// global, product-state encoding init, CX V^T..V cancellation (56 -> 33
// passes), per-(b,w) encoding expm kernel, gates_kernel split over 8 blocks.

namespace {

constexpr int NTB = 512;                 // threads per state block (8 waves)
constexpr int SMEM_BYTES = 80384;        // state 80000 + u 320 + red 32 (+pad)
constexpr double THETA = 0.7853981633974483096; // pi/4

struct cxf { float x, y; };
struct cxd { double x, y; };

// ws float layout:
// [0,100)     V   (V[k*10+m], columns are eigenvectors of a+ad)
// [100,1100)  W   (10 real 10x10 matrices, n-major row-major)
// [1100,2440) BS  packed cxf[670] (per-total-photon blocks)
// [2440,4040) UL  cxf[8*100] fused layer gates (UL[0] pre-fused with V^T)
// [4096,...)  u   cxf[B*4*10] encoded per-(b,w) vectors

__device__ __forceinline__ cxd gen_squeeze(int i, int j, double zr, double zi){
  if (j == i+2){ double g = 0.5*sqrt((double)((i+1)*(i+2))); return {zr*g, -zi*g}; }
  if (i == j+2){ double g = 0.5*sqrt((double)((j+1)*(j+2))); return {-zr*g, -zi*g}; }
  return {0.0, 0.0};
}
__device__ __forceinline__ cxd gen_disp(int i, int j, double ar, double ai){
  if (i == j+1){ double g = sqrt((double)i); return {ar*g, ai*g}; }
  if (j == i+1){ double g = sqrt((double)j); return {-ar*g, ai*g}; }
  return {0.0, 0.0};
}

// BS block geometry (closed-form, avoids dynamically-indexed local arrays).
__device__ __forceinline__ int bs_off(int bn){
  if (bn < 10) return bn*(bn+1)*(2*bn+1)/6;
  int q = 19 - bn;
  return 670 - q*(q+1)*(2*q+1)/6;
}

// Wave-cooperative fixed-schedule expm: result = exp(M), n x n (n<=10).
// Result ends in the ORIGINAL R buffer. Uniform barriers; `act` gates work.
__device__ void expm_fixed(bool act, int n, cxd* M, cxd* P, cxd* T, cxd* R, int lane){
  const int n2 = n*n;
  if (act){
    for (int e=lane; e<n2; e+=64){ M[e].x *= 0x1p-10; M[e].y *= 0x1p-10; }
    for (int e=lane; e<n2; e+=64){
      P[e] = M[e];
      cxd r = M[e];
      if (e % (n+1) == 0) r.x += 1.0;
      R[e] = r;
    }
  }
  __syncthreads();
  for (int t=2; t<=12; ++t){
    if (act){
      double inv = 1.0/(double)t;
      for (int e=lane; e<n2; e+=64){
        int i = e/n, j = e - i*n;
        double ax=0.0, ay=0.0;
        for (int k=0;k<n;k++){
          cxd p = P[i*n+k], m = M[k*n+j];
          ax += p.x*m.x - p.y*m.y;
          ay += p.x*m.y + p.y*m.x;
        }
        T[e] = {ax*inv, ay*inv};
      }
    }
    __syncthreads();
    { cxd* tmp = P; P = T; T = tmp; }
    if (act){ for (int e=lane; e<n2; e+=64){ R[e].x += P[e].x; R[e].y += P[e].y; } }
    __syncthreads();
  }
  for (int s=0; s<10; ++s){
    if (act){
      for (int e=lane; e<n2; e+=64){
        int i = e/n, j = e - i*n;
        double ax=0.0, ay=0.0;
        for (int k=0;k<n;k++){
          cxd p = R[i*n+k], q = R[k*n+j];
          ax += p.x*q.x - p.y*q.y;
          ay += p.x*q.y + p.y*q.x;
        }
        T[e] = {ax, ay};
      }
    }
    __syncthreads();
    { cxd* tmp = R; R = T; T = tmp; }
    __syncthreads();
  }
}

// ------------- Kernel A: shared gate tables into d_ws (8 blocks) -----------
// Tasks: 0..9 W[n]=exp(lam_n*Q); 10..28 BS block bn=t-10; 29..44 layer S/D.
// Blocks 0..6: tasks 4g..4g+3 (one round). Block 7: task 28, then 29..44
// (4 rounds), then the UL fusion (UL[f]=D*S, UL[0] also left-mul V^T).
__global__ __launch_bounds__(256)
void gates_kernel(const float* __restrict__ dmag, const float* __restrict__ dphase,
                  const float* __restrict__ smag, const float* __restrict__ sphase,
                  float* __restrict__ wsf){
  __shared__ double lam[10];
  __shared__ double Vd[100];
  __shared__ double scr[4][4][200];     // [wave][buf] cxd[100]
  __shared__ double layres[16][200];    // S_lay (0..7), D_lay (8..15)
  const int tid = threadIdx.x;
  const int wv = tid >> 6, lane = tid & 63, g = blockIdx.x;
  float* ws_V = wsf;
  float* ws_W = wsf + 100;
  cxf* ws_BS = (cxf*)(wsf + 1100);
  cxf* ws_UL = (cxf*)(wsf + 2440);

  // Eigendecomposition of x = a+ad (every block, redundantly; block 0 exports).
  if (tid < 10){
    double lo = -6.0, hi = 6.0;
    for (int it=0; it<80; ++it){
      double mid = 0.5*(lo+hi);
      int cnt = 0; double q = 1.0;
      for (int i=0;i<10;i++){
        q = -mid - (i ? (double)i/q : 0.0);
        if (fabs(q) < 1e-300) q = -1e-300;
        if (q < 0.0) cnt++;
      }
      if (cnt > tid) hi = mid; else lo = mid;
    }
    double x = 0.5*(lo+hi);
    double p[10];
    p[0] = 1.0; p[1] = x;
    for (int k=1;k<9;k++) p[k+1] = (x*p[k] - sqrt((double)k)*p[k-1]) * (1.0/sqrt((double)(k+1)));
    double nn=0.0; for (int k=0;k<10;k++) nn += p[k]*p[k];
    double inv = 1.0/sqrt(nn);
    lam[tid] = x;
    for (int k=0;k<10;k++){
      Vd[k*10+tid] = p[k]*inv;
      if (g == 0) ws_V[k*10+tid] = (float)(p[k]*inv);
    }
  }
  __syncthreads();

  const int nrounds = (g==7) ? 5 : 1;
  for (int r=0; r<nrounds; ++r){
    int t;
    if (g < 7) t = 4*g + wv;
    else       t = (r==0) ? ((wv==0) ? 28 : 64) : (29 + (r-1)*4 + wv);
    bool act = (t < 45);
    int n = 10, bn = 0, ilo = 0;
    if (act && t >= 10 && t < 29){
      bn = t - 10; ilo = bn < 10 ? 0 : bn - 9;
      int ihi = bn < 10 ? bn : 9;
      n = ihi - ilo + 1;
    }
    cxd* M = (cxd*)scr[wv][0];
    cxd* P = (cxd*)scr[wv][1];
    cxd* T = (cxd*)scr[wv][2];
    cxd* R = (cxd*)scr[wv][3];
    if (act){
      if (t < 10){
        double l = lam[t];   // Q = -0.5*(a - ad)
        for (int e=lane; e<100; e+=64){
          int i=e/10, j=e-10*i;
          double v = 0.0;
          if (j == i+1) v = -0.5*l*sqrt((double)(i+1));
          else if (i == j+1) v = 0.5*l*sqrt((double)i);
          M[e] = {v, 0.0};
        }
      } else if (t < 29){
        for (int e=lane; e<n*n; e+=64){
          int rr=e/n, c=e-n*rr;
          double v = 0.0;
          if (c == rr+1) v = THETA*sqrt((double)((ilo+rr+1)*(bn-ilo-rr)));
          else if (rr == c+1) v = THETA*sqrt((double)((ilo+c+1)*(bn-ilo-c)));
          M[e] = {0.0, v};
        }
      } else {
        int idx = t-29, kind = idx>>3, L=(idx>>2)&1, w=idx&3;
        double r_ = kind ? (double)dmag[L*4+w]   : (double)smag[L*4+w];
        double ph = kind ? (double)dphase[L*4+w] : (double)sphase[L*4+w];
        double zr = r_*cos(ph), zi = r_*sin(ph);
        for (int e=lane; e<100; e+=64){
          int i=e/10, j=e-10*i;
          M[e] = kind ? gen_disp(i,j,zr,zi) : gen_squeeze(i,j,zr,zi);
        }
      }
    }
    __syncthreads();
    expm_fixed(act, n, M, P, T, R, lane);
    if (act){
      if (t < 10){
        for (int e=lane;e<100;e+=64) ws_W[t*100+e] = (float)R[e].x;
      } else if (t < 29){
        int off = bs_off(bn);
        for (int e=lane;e<n*n;e+=64){ cxf o; o.x=(float)R[e].x; o.y=(float)R[e].y; ws_BS[off+e]=o; }
      } else {
        int idx = t-29;
        cxd* dst = (cxd*)layres[idx];
        for (int e=lane;e<100;e+=64) dst[e] = R[e];
      }
    }
    __syncthreads();
  }

  if (g == 7){
    // UL[f] = D_lay * S_lay; UL[0] additionally left-multiplied by V^T
    for (int half=0; half<2; ++half){
      int f = wv + half*4;
      cxd* D  = (cxd*)layres[8+f];
      cxd* Sm = (cxd*)layres[f];
      cxd* prod = (cxd*)scr[wv][0];
      for (int e=lane;e<100;e+=64){
        int i=e/10, j=e-10*i;
        double ax=0, ay=0;
        for (int k=0;k<10;k++){
          cxd d=D[i*10+k], s=Sm[k*10+j];
          ax += d.x*s.x - d.y*s.y;
          ay += d.x*s.y + d.y*s.x;
        }
        prod[e] = {ax, ay};
      }
      __syncthreads();
      for (int e=lane;e<100;e+=64){
        int i=e/10, j=e-10*i;
        double ox, oy;
        if (f == 0){
          ox = 0; oy = 0;
          for (int k=0;k<10;k++){
            double v = Vd[k*10+i];           // (V^T)[i][k] = V[k][i]
            ox += v*prod[k*10+j].x;
            oy += v*prod[k*10+j].y;
          }
        } else { ox = prod[e].x; oy = prod[e].y; }
        cxf o; o.x=(float)ox; o.y=(float)oy;
        ws_UL[f*100+e] = o;
      }
      __syncthreads();
    }
  }
}

// ------------- Kernel B: per-(b,w) encoding vector u = D*(S*e0) ------------
// Block = 128 threads (2 waves): wave0 squeeze expm, wave1 disp expm.
// u0 additionally left-multiplied by V^T (folds layer-0 CX group's V0^T).
__global__ __launch_bounds__(128)
void enc_kernel(const float* __restrict__ jets, const float* __restrict__ sscale,
                float* __restrict__ wsf){
  __shared__ double scr[2][4][200];
  __shared__ double col[20];
  __shared__ double uacc[20];
  const int tid = threadIdx.x, wv = tid>>6, lane = tid&63;
  const int blk = blockIdx.x, b = blk>>2, w = blk&3;

  double eta = (double)jets[b*12 + w*3 + 0];
  double jph = (double)jets[b*12 + w*3 + 1];
  double pt  = (double)jets[b*12 + w*3 + 2];

  cxd* M = (cxd*)scr[wv][0];
  cxd* P = (cxd*)scr[wv][1];
  cxd* T = (cxd*)scr[wv][2];
  cxd* R = (cxd*)scr[wv][3];
  {
    double zr, zi;
    if (wv == 0){ double phs = pt*jph*0.5; zr = eta*cos(phs); zi = eta*sin(phs); }
    else {
      double sc = 10.0/(1.0 + exp(-(double)sscale[0])) + 0.01;
      double mag = sc*pt; zr = mag*cos(eta); zi = mag*sin(eta);
    }
    for (int e=lane; e<100; e+=64){
      int i=e/10, j=e-10*i;
      M[e] = wv ? gen_disp(i,j,zr,zi) : gen_squeeze(i,j,zr,zi);
    }
  }
  __syncthreads();
  expm_fixed(true, 10, M, P, T, R, lane);
  // col = squeeze column 0
  cxd* Rs = (cxd*)scr[0][3];
  cxd* Rd = (cxd*)scr[1][3];
  if (tid < 10){ col[2*tid] = Rs[tid*10].x; col[2*tid+1] = Rs[tid*10].y; }
  __syncthreads();
  if (tid < 10){
    double ax=0, ay=0;
    for (int k=0;k<10;k++){
      cxd d = Rd[tid*10+k];
      double cr = col[2*k], ci = col[2*k+1];
      ax += d.x*cr - d.y*ci;
      ay += d.x*ci + d.y*cr;
    }
    uacc[2*tid] = ax; uacc[2*tid+1] = ay;
  }
  __syncthreads();
  if (tid < 10){
    double rx, ry;
    if (w == 0){
      rx = 0; ry = 0;
      for (int k=0;k<10;k++){
        double v = (double)wsf[k*10 + tid];   // (V^T)[tid][k] = V[k][tid]
        rx += v*uacc[2*k];
        ry += v*uacc[2*k+1];
      }
    } else { rx = uacc[2*tid]; ry = uacc[2*tid+1]; }
    float* u_out = wsf + 4096 + (b*40 + w*10 + tid)*2;
    u_out[0] = (float)rx;
    u_out[1] = (float)ry;
  }
}

// ---------------- Kernel C: the circuit, state-only LDS --------------------

// Single-mode complex gate (matrix from global, wave-uniform -> scalar loads).
__device__ __forceinline__ void apply1_c(cxf* S, const cxf* __restrict__ U, int m, int tid){
  const int sm = (m==0)?1000:((m==1)?100:((m==2)?10:1));
  const int r0 = (m==0)?1:0, r1=(m<=1)?2:1, r2=(m<=2)?3:2;
  const int s0 = (r0==0)?1000:((r0==1)?100:((r0==2)?10:1));
  const int s1 = (r1==0)?1000:((r1==1)?100:((r1==2)?10:1));
  const int s2 = (r2==0)?1000:((r2==1)?100:((r2==2)?10:1));
  for (int f0=0; f0<1024; f0+=NTB){
    int f = f0 + tid;
    if (f < 1000){
      int c0=f/100, rem=f-100*c0, c1=rem/10, c2=rem-10*c1;
      int base = c0*s0 + c1*s1 + c2*s2;
      cxf v[10];
      #pragma unroll
      for (int k=0;k<10;k++) v[k] = S[base + k*sm];
      cxf o[10];
      #pragma unroll
      for (int i=0;i<10;i++){
        float ax=0.f, ay=0.f;
        #pragma unroll
        for (int k=0;k<10;k++){
          cxf u = U[i*10+k];
          ax += u.x*v[k].x - u.y*v[k].y;
          ay += u.x*v[k].y + u.y*v[k].x;
        }
        o[i].x=ax; o[i].y=ay;
      }
      #pragma unroll
      for (int i=0;i<10;i++) S[base + i*sm] = o[i];
    }
  }
}

// Single-mode REAL gate (V or V^T), matrix from global (uniform).
__device__ __forceinline__ void apply1_r(cxf* S, const float* __restrict__ Vm, int m, bool trans, int tid){
  const int sm = (m==0)?1000:((m==1)?100:((m==2)?10:1));
  const int r0 = (m==0)?1:0, r1=(m<=1)?2:1, r2=(m<=2)?3:2;
  const int s0 = (r0==0)?1000:((r0==1)?100:((r0==2)?10:1));
  const int s1 = (r1==0)?1000:((r1==1)?100:((r1==2)?10:1));
  const int s2 = (r2==0)?1000:((r2==1)?100:((r2==2)?10:1));
  for (int f0=0; f0<1024; f0+=NTB){
    int f = f0 + tid;
    if (f < 1000){
      int c0=f/100, rem=f-100*c0, c1=rem/10, c2=rem-10*c1;
      int base = c0*s0 + c1*s1 + c2*s2;
      cxf v[10];
      #pragma unroll
      for (int k=0;k<10;k++) v[k] = S[base + k*sm];
      cxf o[10];
      #pragma unroll
      for (int i=0;i<10;i++){
        float ax=0.f, ay=0.f;
        #pragma unroll
        for (int k=0;k<10;k++){
          float u = trans ? Vm[k*10+i] : Vm[i*10+k];
          ax += u*v[k].x;
          ay += u*v[k].y;
        }
        o[i].x=ax; o[i].y=ay;
      }
      #pragma unroll
      for (int i=0;i<10;i++) S[base + i*sm] = o[i];
    }
  }
}

// Conditional real gate on m2, matrix W[n] (n = eigen-index on m1) from global.
__device__ __forceinline__ void applyW(cxf* S, const float* __restrict__ Wall, int m1, int m2, int tid){
  const int sm = (m2==0)?1000:((m2==1)?100:((m2==2)?10:1));
  const int r0 = (m2==0)?1:0, r1=(m2<=1)?2:1, r2=(m2<=2)?3:2;
  const int s0 = (r0==0)?1000:((r0==1)?100:((r0==2)?10:1));
  const int s1 = (r1==0)?1000:((r1==1)?100:((r1==2)?10:1));
  const int s2 = (r2==0)?1000:((r2==1)?100:((r2==2)?10:1));
  const int pos = (m1==r0)?0:((m1==r1)?1:2);
  for (int f0=0; f0<1024; f0+=NTB){
    int f = f0 + tid;
    if (f < 1000){
      int c0=f/100, rem=f-100*c0, c1=rem/10, c2=rem-10*c1;
      int base = c0*s0 + c1*s1 + c2*s2;
      int n = (pos==0)?c0:((pos==1)?c1:c2);
      const float* __restrict__ Wm = Wall + n*100;
      cxf v[10];
      #pragma unroll
      for (int k=0;k<10;k++) v[k] = S[base + k*sm];
      cxf o[10];
      #pragma unroll
      for (int i=0;i<10;i++){
        float ax=0.f, ay=0.f;
        #pragma unroll
        for (int k=0;k<10;k++){
          float u = Wm[i*10+k];
          ax += u*v[k].x;
          ay += u*v[k].y;
        }
        o[i].x=ax; o[i].y=ay;
      }
      #pragma unroll
      for (int i=0;i<10;i++) S[base + i*sm] = o[i];
    }
  }
}

// Beamsplitter via total-photon blocks; iterate bn-major so lanes share bn.
__device__ __forceinline__ void applyBS(cxf* S, const cxf* __restrict__ BSp, int m1, int m2, int tid){
  int ra=-1, rb=-1;
  for (int q=0;q<4;q++) if (q!=m1 && q!=m2){ if (ra<0) ra=q; else rb=q; }
  const int sa = (ra==0)?1000:((ra==1)?100:((ra==2)?10:1));
  const int sb = (rb==0)?1000:((rb==1)?100:((rb==2)?10:1));
  const int s1 = (m1==0)?1000:((m1==1)?100:((m1==2)?10:1));
  const int s2 = (m2==0)?1000:((m2==1)?100:((m2==2)?10:1));
  for (int w0=0; w0<2048; w0+=NTB){
    int it = w0 + tid;
    if (it < 1900){
      int bn = it/100, rest = it-100*bn;
      int ilo = bn<10?0:bn-9, ihi = bn<10?bn:9, sz = ihi-ilo+1;
      int ca = rest/10, cb = rest-10*ca;
      int base = ca*sa + cb*sb;
      const cxf* __restrict__ Bn = BSp + bs_off(bn);
      cxf v[10];
      #pragma unroll
      for (int r=0;r<10;r++){
        if (r < sz){ int i=ilo+r; v[r] = S[base + i*s1 + (bn-i)*s2]; }
      }
      cxf o[10];
      #pragma unroll
      for (int r=0;r<10;r++){
        if (r < sz){
          float ax=0.f, ay=0.f;
          for (int c=0;c<sz;c++){
            cxf u = Bn[r*sz+c];
            ax += u.x*v[c].x - u.y*v[c].y;
            ay += u.x*v[c].y + u.y*v[c].x;
          }
          o[r].x=ax; o[r].y=ay;
        }
      }
      #pragma unroll
      for (int r=0;r<10;r++){
        if (r < sz){ int i=ilo+r; S[base + i*s1 + (bn-i)*s2] = o[r]; }
      }
    }
  }
}

__global__ __launch_bounds__(NTB, 4)
void state_kernel(const float* __restrict__ wd, const float* __restrict__ bd,
                  const float* __restrict__ wsf, float* __restrict__ out){
  extern __shared__ __align__(16) char smem[];
  cxf* S    = (cxf*)smem;                 // 10000 cxf (80000 B)
  cxf* uv   = (cxf*)(smem + 80000);       // 4*10 encoding vectors
  float* red = (float*)(smem + 80320);    // 8

  const float* __restrict__ V  = wsf;
  const float* __restrict__ W  = wsf + 100;
  const cxf*   __restrict__ BSm = (const cxf*)(wsf + 1100);
  const cxf*   __restrict__ UL  = (const cxf*)(wsf + 2440);
  const cxf*   __restrict__ uw  = (const cxf*)(wsf + 4096);

  const int tid = threadIdx.x, wv = tid>>6, lane = tid&63;
  const int b = blockIdx.x;

  if (tid < 40) uv[tid] = uw[b*40 + tid];
  __syncthreads();

  // Init: product state S = u0 (x) u1 (x) u2 (x) u3  (V0^T already folded in u0)
  for (int e=tid; e<10000; e+=NTB){
    int c0=e/1000, r_=e-1000*c0, c1=r_/100, r2_=r_-100*c1, c2=r2_/10, c3=r2_-10*c2;
    cxf A = uv[c0], B = uv[10+c1], C = uv[20+c2], D = uv[30+c3];
    float pr = A.x*B.x - A.y*B.y, pi = A.x*B.y + A.y*B.x;
    float qr = pr*C.x - pi*C.y,  qi = pr*C.y + pi*C.x;
    cxf o; o.x = qr*D.x - qi*D.y; o.y = qr*D.y + qi*D.x;
    S[e] = o;
  }
  __syncthreads();

  for (int L=0; L<2; ++L){
    // CX group a=0 (V0^T folded into u0 / UL[0]):
    applyW(S, W, 0, 1, tid); __syncthreads();
    applyW(S, W, 0, 2, tid); __syncthreads();
    applyW(S, W, 0, 3, tid); __syncthreads();
    apply1_r(S, V, 0, false, tid); __syncthreads();
    // a=1:
    apply1_r(S, V, 1, true, tid); __syncthreads();
    applyW(S, W, 1, 2, tid); __syncthreads();
    applyW(S, W, 1, 3, tid); __syncthreads();
    apply1_r(S, V, 1, false, tid); __syncthreads();
    // a=2:
    apply1_r(S, V, 2, true, tid); __syncthreads();
    applyW(S, W, 2, 3, tid); __syncthreads();
    apply1_r(S, V, 2, false, tid); __syncthreads();
    // Beamsplitters:
    applyBS(S, BSm, 0, 1, tid); __syncthreads();
    applyBS(S, BSm, 1, 2, tid); __syncthreads();
    applyBS(S, BSm, 2, 3, tid); __syncthreads();
    applyBS(S, BSm, 3, 0, tid); __syncthreads();
    // Layer single-mode gates (UL[0] carries next layer's V0^T):
    for (int w=0; w<4; ++w){ apply1_c(S, UL + (L*4+w)*100, w, tid); __syncthreads(); }
  }

  float w0 = wd[0], w1 = wd[1], w2 = wd[2];
  float acc = 0.f;
  for (int e=tid; e<10000; e+=NTB){
    cxf z = S[e];
    float p = z.x*z.x + z.y*z.y;
    int n0 = e/1000, r_ = e-1000*n0, n1 = r_/100, r2_ = r_-100*n1, n2 = r2_/10;
    acc += p * ((float)n0*w0 + (float)n1*w1 + (float)n2*w2);
  }
  for (int off=32; off; off>>=1) acc += __shfl_down(acc, off, 64);
  if (lane == 0) red[wv] = acc;
  __syncthreads();
  if (tid == 0){
    float s = 0.f;
    for (int i=0;i<8;i++) s += red[i];
    out[b] = s + bd[0];
  }
}

} // anonymous namespace

extern "C" void kernel_launch(void* const* d_in, const int* in_sizes, int n_in,
                              void* d_out, int out_size, void* d_ws, size_t ws_size,
                              hipStream_t stream){
  const float* jets   = (const float*)d_in[0];
  const float* sscale = (const float*)d_in[1];
  const float* dmag   = (const float*)d_in[2];
  const float* dphase = (const float*)d_in[3];
  const float* smag   = (const float*)d_in[4];
  const float* sphase = (const float*)d_in[5];
  const float* wd     = (const float*)d_in[6];
  const float* bd     = (const float*)d_in[7];
  float* out = (float*)d_out;
  float* wsf = (float*)d_ws;
  int B = in_sizes[0] / 12;

  (void)hipFuncSetAttribute(reinterpret_cast<const void*>(&state_kernel),
                            hipFuncAttributeMaxDynamicSharedMemorySize, SMEM_BYTES);

  gates_kernel<<<8, 256, 0, stream>>>(dmag, dphase, smag, sphase, wsf);
  enc_kernel<<<B*4, 128, 0, stream>>>(jets, sscale, wsf);
  state_kernel<<<B, NTB, SMEM_BYTES, stream>>>(wd, bd, wsf, out);
}